// Round 3
// baseline (3503.755 us; speedup 1.0000x reference)
//
#include <hip/hip_runtime.h>

// ---------------------------------------------------------------------------
// MultiDQNGNN: states[2048,16,30,30] -> conv(16->16->32->16->16, 3x3 VALID,
// ReLU) -> flatten 7744 -> MLP 128,128,128 -> GCN (sym-norm) -> head 128,128,5
// All f32. One block per image fuses the whole conv chain in LDS.
// Round 3: FIX stage-1 weight staging (288 entries, only 256 threads -> the
// old `if (t<288) sW[t]=...` left sW[256..287] uninitialized, corrupting conv1
// oc 28-31). Also hardened mask decode for u8/i32/i64/bf16/f32/f64 layouts.
// ---------------------------------------------------------------------------

// ============== Kernel 0: decode `inactives` regardless of layout ==========
// Classify the upload layout from the first 2048 bytes (in-bounds under every
// candidate encoding: >=1 byte/elem, 2048 elems), then normalize to int32 0/1.
// Byte-pattern signatures (values are only 0 or 1 / 0.0 or 1.0):
//   u8  : bytes {0,1} at all offsets       i32: {0,1} at %4==0 only
//   i64 : {0,1} at %8==0 only              bf16: 0x80 at even, 0x3F at odd
//   f32 : 0x80 at %4==2, 0x3F at %4==3     f64 : 0xF0 at %8==6, 0x3F at %8==7
__global__ void k_mask(const void* __restrict__ raw, int* __restrict__ mask)
{
    __shared__ unsigned pat[8];
    __shared__ int layout;
    const unsigned char* bts = (const unsigned char*)raw;
    const unsigned* w = (const unsigned*)raw;
    const unsigned short* hw = (const unsigned short*)raw;
    const int t = threadIdx.x;
    if (t < 8) pat[t] = 0;
    __syncthreads();
    unsigned loc[8] = {0,0,0,0,0,0,0,0};
    for (int i = t * 8; i < 2048; i += 256 * 8)
#pragma unroll
        for (int r = 0; r < 8; ++r) loc[r] |= bts[i + r];
#pragma unroll
    for (int r = 0; r < 8; ++r) if (loc[r]) atomicOr(&pat[r], loc[r]);
    __syncthreads();
    if (t == 0) {
        int L = 0;  // default int32
        bool smallOnly = true;
#pragma unroll
        for (int r = 0; r < 8; ++r) smallOnly = smallOnly && (pat[r] <= 1u);
        if (smallOnly) {
            if (pat[1] | pat[2] | pat[3] | pat[5] | pat[6] | pat[7]) L = 1;      // u8
            else if (pat[4] == 0 && pat[0])                          L = 2;      // i64
            else                                                     L = 0;      // i32
        } else {
            if (pat[1] | pat[5])      L = 4;   // bf16 (nonzero at %4==1)
            else if (pat[2] | pat[6]) L = 3;   // f32  (0x80 at %4==2)
            else if (pat[7])          L = 5;   // f64  (high bytes of 8B elems)
        }
        layout = L;
    }
    __syncthreads();
    const int L = layout;
    for (int m = t; m < 2048; m += 256) {
        unsigned v;
        if      (L == 1) v = bts[m];
        else if (L == 2) v = w[2 * m] | w[2 * m + 1];
        else if (L == 3) v = w[m];
        else if (L == 4) v = hw[m];
        else if (L == 5) v = w[2 * m] | w[2 * m + 1];
        else             v = w[m];
        mask[m] = (v != 0u);
    }
}

// ======================= Kernel 1: fused conv chain ========================
__global__ __launch_bounds__(256, 2)
void k_convs(const float* __restrict__ st,
             const float* __restrict__ cw0, const float* __restrict__ cb0,
             const float* __restrict__ cw1, const float* __restrict__ cb1,
             const float* __restrict__ cw2, const float* __restrict__ cb2,
             const float* __restrict__ cw3, const float* __restrict__ cb3,
             float* __restrict__ y3)
{
    __shared__ float arena[13732];
    float* const sY  = arena;          // y0: 16*784=12544 floats; later y2: 16*576=9216
    float* const sCh = arena + 12544;  // staging channel: 900 (conv0 in) / 676 (y1 ch)
    float* const sW  = arena + 13444;  // weight slice, up to 288

    const int t  = threadIdx.x;
    const int bi = blockIdx.x;
    const int gbase = bi * 14400;      // 16 ch * 900

    // ---------------- stage 0: conv0 16ic,30x30 -> 16oc,28x28 ----------------
    const int tp0 = t & 63, tg0 = t >> 6;    // 64 pos-lanes x 4 oc-groups
    int pb0[13];
#pragma unroll
    for (int pi = 0; pi < 13; ++pi) {
        int p = tp0 + pi * 64; if (p >= 784) p = 0;
        pb0[pi] = (p / 28) * 30 + (p % 28);
    }
    float acc0[4][13];
#pragma unroll
    for (int j = 0; j < 4; ++j)
#pragma unroll
        for (int pi = 0; pi < 13; ++pi) acc0[j][pi] = 0.f;

    for (int ic = 0; ic < 16; ++ic) {
#pragma unroll
        for (int r = 0; r < 4; ++r) {
            int i = t + r * 256;
            if (i < 900) sCh[i] = st[gbase + ic * 900 + i];
        }
        if (t < 144) sW[t] = cw0[((t / 9) * 16 + ic) * 9 + (t % 9)];
        __syncthreads();
        float wr[4][9];
#pragma unroll
        for (int j = 0; j < 4; ++j)
#pragma unroll
            for (int k = 0; k < 9; ++k) wr[j][k] = sW[(tg0 * 4 + j) * 9 + k];
#pragma unroll
        for (int pi = 0; pi < 13; ++pi) {
            const int ib = pb0[pi];
            float in9[9];
#pragma unroll
            for (int ky = 0; ky < 3; ++ky)
#pragma unroll
                for (int kx = 0; kx < 3; ++kx) in9[ky * 3 + kx] = sCh[ib + ky * 30 + kx];
#pragma unroll
            for (int j = 0; j < 4; ++j)
#pragma unroll
                for (int k = 0; k < 9; ++k) acc0[j][pi] = fmaf(wr[j][k], in9[k], acc0[j][pi]);
        }
        __syncthreads();
    }
    {
        float bv[4];
#pragma unroll
        for (int j = 0; j < 4; ++j) bv[j] = cb0[tg0 * 4 + j];
#pragma unroll
        for (int pi = 0; pi < 13; ++pi) {
            int p = tp0 + pi * 64;
            if (p < 784) {
#pragma unroll
                for (int j = 0; j < 4; ++j)
                    sY[(tg0 * 4 + j) * 784 + p] = fmaxf(acc0[j][pi] + bv[j], 0.f);
            }
        }
    }
    __syncthreads();

    // ---------------- stage 1: conv1 16ic,28x28 -> 32oc,26x26 ----------------
    const int tp1 = t & 31, tg1 = t >> 5;    // 32 pos-lanes x 8 oc-groups
    int pb1[22];
#pragma unroll
    for (int pi = 0; pi < 22; ++pi) {
        int p = tp1 + pi * 32; if (p >= 676) p = 0;
        pb1[pi] = (p / 26) * 28 + (p % 26);
    }
    float acc1[4][22];
#pragma unroll
    for (int j = 0; j < 4; ++j)
#pragma unroll
        for (int pi = 0; pi < 22; ++pi) acc1[j][pi] = 0.f;

    for (int ic = 0; ic < 16; ++ic) {
        // 288 weight entries, 256 threads -> strided loop (round-3 fix)
        for (int e = t; e < 288; e += 256)
            sW[e] = cw1[((e / 9) * 16 + ic) * 9 + (e % 9)];
        __syncthreads();
        float wr[4][9];
#pragma unroll
        for (int j = 0; j < 4; ++j)
#pragma unroll
            for (int k = 0; k < 9; ++k) wr[j][k] = sW[(tg1 * 4 + j) * 9 + k];
        const float* y0c = sY + ic * 784;
#pragma unroll
        for (int pi = 0; pi < 22; ++pi) {
            const int ib = pb1[pi];
            float in9[9];
#pragma unroll
            for (int ky = 0; ky < 3; ++ky)
#pragma unroll
                for (int kx = 0; kx < 3; ++kx) in9[ky * 3 + kx] = y0c[ib + ky * 28 + kx];
#pragma unroll
            for (int j = 0; j < 4; ++j)
#pragma unroll
                for (int k = 0; k < 9; ++k) acc1[j][pi] = fmaf(wr[j][k], in9[k], acc1[j][pi]);
        }
        __syncthreads();
    }
    {
        float bv[4];
#pragma unroll
        for (int j = 0; j < 4; ++j) bv[j] = cb1[tg1 * 4 + j];
#pragma unroll
        for (int j = 0; j < 4; ++j)
#pragma unroll
            for (int pi = 0; pi < 22; ++pi) acc1[j][pi] = fmaxf(acc1[j][pi] + bv[j], 0.f);
    }

    // ---------------- stage 2: conv2 32ic,26x26 -> 16oc,24x24 ----------------
    // y1 lives in registers (acc1, distributed); channel-stage through sCh.
    const int tp2 = t & 63, tg2 = t >> 6;    // 64 pos-lanes x 4 oc-groups, 9 pos each
    int pb2[9];
#pragma unroll
    for (int pi = 0; pi < 9; ++pi) {
        int p = tp2 + pi * 64;               // 64*9 = 576 exact
        pb2[pi] = (p / 24) * 26 + (p % 24);
    }
    float acc2[4][9];
#pragma unroll
    for (int j = 0; j < 4; ++j)
#pragma unroll
        for (int pi = 0; pi < 9; ++pi) acc2[j][pi] = 0.f;

    for (int g = 0; g < 8; ++g) {
#pragma unroll
        for (int jj = 0; jj < 4; ++jj) {
            const int ic = g * 4 + jj;
            if ((t >> 5) == g) {             // owning group stages its channel
#pragma unroll
                for (int pi = 0; pi < 22; ++pi) {
                    int p = (t & 31) + pi * 32;
                    if (p < 676) sCh[p] = acc1[jj][pi];
                }
            }
            if (t < 144) sW[t] = cw2[((t / 9) * 32 + ic) * 9 + (t % 9)];
            __syncthreads();
            float wr[4][9];
#pragma unroll
            for (int j = 0; j < 4; ++j)
#pragma unroll
                for (int k = 0; k < 9; ++k) wr[j][k] = sW[(tg2 * 4 + j) * 9 + k];
#pragma unroll
            for (int pi = 0; pi < 9; ++pi) {
                const int ib = pb2[pi];
                float in9[9];
#pragma unroll
                for (int ky = 0; ky < 3; ++ky)
#pragma unroll
                    for (int kx = 0; kx < 3; ++kx) in9[ky * 3 + kx] = sCh[ib + ky * 26 + kx];
#pragma unroll
                for (int j = 0; j < 4; ++j)
#pragma unroll
                    for (int k = 0; k < 9; ++k) acc2[j][pi] = fmaf(wr[j][k], in9[k], acc2[j][pi]);
            }
            __syncthreads();
        }
    }
    {
        float bv[4];
#pragma unroll
        for (int j = 0; j < 4; ++j) bv[j] = cb2[tg2 * 4 + j];
#pragma unroll
        for (int pi = 0; pi < 9; ++pi) {
            int p = tp2 + pi * 64;
#pragma unroll
            for (int j = 0; j < 4; ++j)
                sY[(tg2 * 4 + j) * 576 + p] = fmaxf(acc2[j][pi] + bv[j], 0.f);  // y2
        }
    }
    __syncthreads();

    // ---------------- stage 3: conv3 16ic,24x24 -> 16oc,22x22 ----------------
    const int tp3 = t & 63, tg3 = t >> 6;
    int pb3[8];
#pragma unroll
    for (int pi = 0; pi < 8; ++pi) {
        int p = tp3 + pi * 64; if (p >= 484) p = 0;
        pb3[pi] = (p / 22) * 24 + (p % 22);
    }
    float acc3[4][8];
#pragma unroll
    for (int j = 0; j < 4; ++j)
#pragma unroll
        for (int pi = 0; pi < 8; ++pi) acc3[j][pi] = 0.f;

    for (int ic = 0; ic < 16; ++ic) {
        if (t < 144) sW[t] = cw3[((t / 9) * 16 + ic) * 9 + (t % 9)];
        __syncthreads();
        float wr[4][9];
#pragma unroll
        for (int j = 0; j < 4; ++j)
#pragma unroll
            for (int k = 0; k < 9; ++k) wr[j][k] = sW[(tg3 * 4 + j) * 9 + k];
        const float* y2c = sY + ic * 576;
#pragma unroll
        for (int pi = 0; pi < 8; ++pi) {
            const int ib = pb3[pi];
            float in9[9];
#pragma unroll
            for (int ky = 0; ky < 3; ++ky)
#pragma unroll
                for (int kx = 0; kx < 3; ++kx) in9[ky * 3 + kx] = y2c[ib + ky * 24 + kx];
#pragma unroll
            for (int j = 0; j < 4; ++j)
#pragma unroll
                for (int k = 0; k < 9; ++k) acc3[j][pi] = fmaf(wr[j][k], in9[k], acc3[j][pi]);
        }
        __syncthreads();
    }
    {
        float bv[4];
#pragma unroll
        for (int j = 0; j < 4; ++j) bv[j] = cb3[tg3 * 4 + j];
#pragma unroll
        for (int pi = 0; pi < 8; ++pi) {
            int p = tp3 + pi * 64;
            if (p < 484) {
#pragma unroll
                for (int j = 0; j < 4; ++j)
                    y3[bi * 7744 + (tg3 * 4 + j) * 484 + p] = fmaxf(acc3[j][pi] + bv[j], 0.f);
            }
        }
    }
}

// ================= Kernel 2: MLP0 GEMM, M=2048 K=7744 N=128, K-split 8 =====
__global__ __launch_bounds__(256)
void k_mlp0(const float* __restrict__ y3, const float* __restrict__ mw0,
            float* __restrict__ part)
{
    __shared__ float As[8 * 32];    // As[kk][m], Mtile=32
    __shared__ float Bs[8 * 128];   // Bs[kk][n]
    const int t  = threadIdx.x;
    const int mt = blockIdx.x;      // 64 M-tiles
    const int ks = blockIdx.y;      // 8  K-splits
    const int m0g = mt * 32;
    const int kb0 = ks * 968;
    const int tm = t >> 4, tn = t & 15;
    const int m0 = tm * 2, n0 = tn * 8;
    float acc[2][8];
#pragma unroll
    for (int r = 0; r < 2; ++r)
#pragma unroll
        for (int c = 0; c < 8; ++c) acc[r][c] = 0.f;

    for (int it = 0; it < 121; ++it) {   // 121 * 8 = 968
        const int kb = kb0 + it * 8;
        if (t < 64) {
            int m = t >> 1, q = t & 1;
            const float4 a4 = *(const float4*)&y3[(m0g + m) * 7744 + kb + q * 4];
            As[(q * 4 + 0) * 32 + m] = a4.x;
            As[(q * 4 + 1) * 32 + m] = a4.y;
            As[(q * 4 + 2) * 32 + m] = a4.z;
            As[(q * 4 + 3) * 32 + m] = a4.w;
        }
        {
            int kk = t >> 5, n4 = t & 31;
            *(float4*)&Bs[kk * 128 + n4 * 4] = *(const float4*)&mw0[(kb + kk) * 128 + n4 * 4];
        }
        __syncthreads();
#pragma unroll
        for (int kk = 0; kk < 8; ++kk) {
            float a0 = As[kk * 32 + m0];
            float a1 = As[kk * 32 + m0 + 1];
            float4 b0 = *(const float4*)&Bs[kk * 128 + n0];
            float4 b1 = *(const float4*)&Bs[kk * 128 + n0 + 4];
            float br[8] = {b0.x, b0.y, b0.z, b0.w, b1.x, b1.y, b1.z, b1.w};
#pragma unroll
            for (int c = 0; c < 8; ++c) {
                acc[0][c] = fmaf(a0, br[c], acc[0][c]);
                acc[1][c] = fmaf(a1, br[c], acc[1][c]);
            }
        }
        __syncthreads();
    }
#pragma unroll
    for (int r = 0; r < 2; ++r)
#pragma unroll
        for (int c = 0; c < 8; ++c)
            part[ks * 262144 + (m0g + m0 + r) * 128 + n0 + c] = acc[r][c];
}

__global__ void k_red(const float* __restrict__ part, const float* __restrict__ mb0,
                      float* __restrict__ z0)
{
    int idx = blockIdx.x * 256 + threadIdx.x;   // 262144 total
    int n = idx & 127;
    float s = mb0[n];
#pragma unroll
    for (int k = 0; k < 8; ++k) s += part[k * 262144 + idx];
    z0[idx] = fmaxf(s, 0.f);
}

// ============ Kernel 3: generic [2048x128] @ [128x128] + bias + act ========
__global__ __launch_bounds__(256)
void k_fc(const float* __restrict__ A, const float* __restrict__ W,
          const float* __restrict__ bias, float* __restrict__ C, int do_relu)
{
    __shared__ float As[32 * 129];   // padded to kill bank conflicts
    __shared__ float Ws[32 * 128];
    const int t = threadIdx.x;
    const int m0g = blockIdx.x * 32;
#pragma unroll
    for (int r = 0; r < 16; ++r) {
        int e = t + r * 256; int m = e >> 7, k = e & 127;
        As[m * 129 + k] = A[(m0g + m) * 128 + k];
    }
    const int tm = t >> 4, tn = t & 15;
    const int m0 = tm * 2, n0 = tn * 8;
    float acc[2][8];
#pragma unroll
    for (int r = 0; r < 2; ++r)
#pragma unroll
        for (int c = 0; c < 8; ++c) acc[r][c] = 0.f;

    for (int kc = 0; kc < 4; ++kc) {
        __syncthreads();
#pragma unroll
        for (int r = 0; r < 16; ++r) {
            int e = t + r * 256; int kk = e >> 7, n = e & 127;
            Ws[kk * 128 + n] = W[(kc * 32 + kk) * 128 + n];
        }
        __syncthreads();
#pragma unroll
        for (int kk = 0; kk < 32; ++kk) {
            float a0 = As[(m0 + 0) * 129 + kc * 32 + kk];
            float a1 = As[(m0 + 1) * 129 + kc * 32 + kk];
            float4 b0 = *(const float4*)&Ws[kk * 128 + n0];
            float4 b1 = *(const float4*)&Ws[kk * 128 + n0 + 4];
            float br[8] = {b0.x, b0.y, b0.z, b0.w, b1.x, b1.y, b1.z, b1.w};
#pragma unroll
            for (int c = 0; c < 8; ++c) {
                acc[0][c] = fmaf(a0, br[c], acc[0][c]);
                acc[1][c] = fmaf(a1, br[c], acc[1][c]);
            }
        }
    }
#pragma unroll
    for (int c = 0; c < 8; ++c) {
        float bv = bias ? bias[n0 + c] : 0.f;
#pragma unroll
        for (int r = 0; r < 2; ++r) {
            float v = acc[r][c] + bv;
            if (do_relu) v = fmaxf(v, 0.f);
            C[(m0g + m0 + r) * 128 + n0 + c] = v;
        }
    }
}

// ======================= Kernel 4: degree -> dis ===========================
__global__ void k_dis(const float* __restrict__ adj, float* __restrict__ dis)
{
    int bj = blockIdx.x * 256 + threadIdx.x;    // 2048
    int b = bj >> 6, j = bj & 63;
    float s = 0.f;
#pragma unroll 4
    for (int i = 0; i < 64; ++i) s += adj[b * 4096 + i * 64 + j];
    dis[bj] = s > 0.f ? rsqrtf(fmaxf(s, 1e-30f)) : 0.f;
}

// =========== Kernel 5: emb[b,j,d] = dis_j * sum_i dis_i A[i,j] h[i,d] + gb =
__global__ __launch_bounds__(256)
void k_gcn(const float* __restrict__ adj, const float* __restrict__ dis,
           const float* __restrict__ h, const float* __restrict__ gb,
           float* __restrict__ emb)
{
    __shared__ float adjn[64 * 64];
    __shared__ float hS[64 * 128];
    __shared__ float disS[64];
    const int t = threadIdx.x;
    const int b = blockIdx.x;
    if (t < 64) disS[t] = dis[b * 64 + t];
    __syncthreads();
#pragma unroll
    for (int r = 0; r < 16; ++r) {
        int e = t + r * 256; int i = e >> 6;
        adjn[e] = adj[b * 4096 + e] * disS[i];   // dis_i * A[i,j]
    }
#pragma unroll
    for (int r = 0; r < 32; ++r) {
        int e = t + r * 256;
        hS[e] = h[b * 8192 + e];
    }
    __syncthreads();
    const int tj = t >> 5, tn = t & 31;
    const int j0 = tj * 8, n0 = tn * 4;
    float acc[8][4];
#pragma unroll
    for (int jj = 0; jj < 8; ++jj)
#pragma unroll
        for (int c = 0; c < 4; ++c) acc[jj][c] = 0.f;
    for (int i = 0; i < 64; ++i) {
        float4 h4 = *(const float4*)&hS[i * 128 + n0];
        float hr[4] = {h4.x, h4.y, h4.z, h4.w};
#pragma unroll
        for (int jj = 0; jj < 8; ++jj) {
            float a = adjn[i * 64 + j0 + jj];
#pragma unroll
            for (int c = 0; c < 4; ++c) acc[jj][c] = fmaf(a, hr[c], acc[jj][c]);
        }
    }
#pragma unroll
    for (int jj = 0; jj < 8; ++jj) {
        float dj = disS[j0 + jj];
#pragma unroll
        for (int c = 0; c < 4; ++c)
            emb[b * 8192 + (j0 + jj) * 128 + n0 + c] = dj * acc[jj][c] + gb[n0 + c];
    }
}

// ============== Kernel 6: final 128->5 + inactive mask =====================
__global__ __launch_bounds__(256)
void k_head(const float* __restrict__ q1, const float* __restrict__ fw2,
            const float* __restrict__ fb2, const int* __restrict__ maskN,
            float* __restrict__ out)
{
    __shared__ float qs[256 * 33];
    __shared__ float w2s[640];
    __shared__ float b2s[5];
    const int t = threadIdx.x;
    const int m0g = blockIdx.x * 256;
    if (t < 5) b2s[t] = fb2[t];
#pragma unroll
    for (int r = 0; r < 3; ++r) {
        int e = t + r * 256;
        if (e < 640) w2s[e] = fw2[e];
    }
    float acc[5] = {0.f, 0.f, 0.f, 0.f, 0.f};
    for (int kc = 0; kc < 4; ++kc) {
        __syncthreads();
#pragma unroll
        for (int r = 0; r < 32; ++r) {
            int e = t + r * 256; int m = e >> 5, k = e & 31;
            qs[m * 33 + k] = q1[(m0g + m) * 128 + kc * 32 + k];
        }
        __syncthreads();
#pragma unroll
        for (int k = 0; k < 32; ++k) {
            float v = qs[t * 33 + k];
#pragma unroll
            for (int a = 0; a < 5; ++a) acc[a] = fmaf(v, w2s[(kc * 32 + k) * 5 + a], acc[a]);
        }
    }
    const int m = m0g + t;
    const int iz = maskN[m];
#pragma unroll
    for (int a = 0; a < 5; ++a) out[m * 5 + a] = iz ? 0.f : (acc[a] + b2s[a]);
}

// ===========================================================================
extern "C" void kernel_launch(void* const* d_in, const int* in_sizes, int n_in,
                              void* d_out, int out_size, void* d_ws, size_t ws_size,
                              hipStream_t stream)
{
    (void)in_sizes; (void)n_in; (void)out_size; (void)ws_size;
    const float* states = (const float*)d_in[0];
    const float* adj    = (const float*)d_in[1];
    const void*  inact  = (const void*) d_in[2];
    const float* cw0 = (const float*)d_in[3];  const float* cb0 = (const float*)d_in[4];
    const float* cw1 = (const float*)d_in[5];  const float* cb1 = (const float*)d_in[6];
    const float* cw2 = (const float*)d_in[7];  const float* cb2 = (const float*)d_in[8];
    const float* cw3 = (const float*)d_in[9];  const float* cb3 = (const float*)d_in[10];
    const float* mw0 = (const float*)d_in[11]; const float* mb0 = (const float*)d_in[12];
    const float* mw1 = (const float*)d_in[13]; const float* mb1 = (const float*)d_in[14];
    const float* mw2 = (const float*)d_in[15]; const float* mb2 = (const float*)d_in[16];
    const float* gw  = (const float*)d_in[17]; const float* gb  = (const float*)d_in[18];
    const float* fw0 = (const float*)d_in[19]; const float* fb0 = (const float*)d_in[20];
    const float* fw1 = (const float*)d_in[21]; const float* fb1 = (const float*)d_in[22];
    const float* fw2 = (const float*)d_in[23]; const float* fb2 = (const float*)d_in[24];
    float* out = (float*)d_out;

    // workspace layout (floats): total ~79.3 MB
    float* ws    = (float*)d_ws;
    float* y3    = ws;                       // 2048*7744   = 15,859,712
    float* part  = y3   + 15859712;          // 8*2048*128  =  2,097,152
    float* z0    = part + 2097152;           // 262,144 each below
    float* z1    = z0   + 262144;
    float* feats = z1   + 262144;
    float* h     = feats+ 262144;
    float* emb   = h    + 262144;
    float* q0    = emb  + 262144;
    float* q1    = q0   + 262144;
    float* dis   = q1   + 262144;            // 2048
    int*   maskN = (int*)(dis + 2048);       // 2048 ints

    k_mask <<<1, 256, 0, stream>>>(inact, maskN);
    k_convs<<<2048, 256, 0, stream>>>(states, cw0, cb0, cw1, cb1, cw2, cb2, cw3, cb3, y3);
    k_mlp0<<<dim3(64, 8), 256, 0, stream>>>(y3, mw0, part);
    k_red<<<1024, 256, 0, stream>>>(part, mb0, z0);
    k_fc<<<64, 256, 0, stream>>>(z0, mw1, mb1, z1, 1);
    k_fc<<<64, 256, 0, stream>>>(z1, mw2, mb2, feats, 0);
    k_fc<<<64, 256, 0, stream>>>(feats, gw, nullptr, h, 0);
    k_dis<<<8, 256, 0, stream>>>(adj, dis);
    k_gcn<<<32, 256, 0, stream>>>(adj, dis, h, gb, emb);
    k_fc<<<64, 256, 0, stream>>>(emb, fw0, fb0, q0, 1);
    k_fc<<<64, 256, 0, stream>>>(q0, fw1, fb1, q1, 1);
    k_head<<<8, 256, 0, stream>>>(q1, fw2, fb2, maskN, out);
}

// Round 5
// 1033.112 us; speedup vs baseline: 3.3915x; 3.3915x over previous
//
#include <hip/hip_runtime.h>

// ---------------------------------------------------------------------------
// MultiDQNGNN. Round 5: fix workspace overlay (round-4 bug: maskN/dis lived
// inside the y1 dynamic region -> k_convA clobbered the mask -> outputs
// mostly zeroed). Header [maskN][dis] now precedes y3 + dynamic region.
// Conv chain: two spill-free kernels, 2 ocs x 1 row per thread, sliding
// window with b128 LDS reads, y1 streamed via workspace (ws-adaptive split).
// ---------------------------------------------------------------------------

// ============== Kernel 0: decode `inactives` regardless of layout ==========
__global__ void k_mask(const void* __restrict__ raw, int* __restrict__ mask)
{
    __shared__ unsigned pat[8];
    __shared__ int layout;
    const unsigned char* bts = (const unsigned char*)raw;
    const unsigned* w = (const unsigned*)raw;
    const unsigned short* hw = (const unsigned short*)raw;
    const int t = threadIdx.x;
    if (t < 8) pat[t] = 0;
    __syncthreads();
    unsigned loc[8] = {0,0,0,0,0,0,0,0};
    for (int i = t * 8; i < 2048; i += 256 * 8)
#pragma unroll
        for (int r = 0; r < 8; ++r) loc[r] |= bts[i + r];
#pragma unroll
    for (int r = 0; r < 8; ++r) if (loc[r]) atomicOr(&pat[r], loc[r]);
    __syncthreads();
    if (t == 0) {
        int L = 0;
        bool smallOnly = true;
#pragma unroll
        for (int r = 0; r < 8; ++r) smallOnly = smallOnly && (pat[r] <= 1u);
        if (smallOnly) {
            if (pat[1] | pat[2] | pat[3] | pat[5] | pat[6] | pat[7]) L = 1;  // u8
            else if (pat[4] == 0 && pat[0])                          L = 2;  // i64
            else                                                     L = 0;  // i32
        } else {
            if (pat[1] | pat[5])      L = 4;   // bf16
            else if (pat[2] | pat[6]) L = 3;   // f32
            else if (pat[7])          L = 5;   // f64
        }
        layout = L;
    }
    __syncthreads();
    const int L = layout;
    for (int m = t; m < 2048; m += 256) {
        unsigned v;
        if      (L == 1) v = bts[m];
        else if (L == 2) v = w[2 * m] | w[2 * m + 1];
        else if (L == 3) v = w[m];
        else if (L == 4) v = hw[m];
        else if (L == 5) v = w[2 * m] | w[2 * m + 1];
        else             v = w[m];
        mask[m] = (v != 0u);
    }
}

// ================= sliding-window row sweep (2 ocs, one row) ===============
template<int OW>
__device__ __forceinline__ void row_sweep(
    const float* __restrict__ r0, const float* __restrict__ r1,
    const float* __restrict__ r2,
    const float* __restrict__ w0, const float* __restrict__ w1,
    float* __restrict__ acc0, float* __restrict__ acc1)
{
    float a[3][8] __attribute__((aligned(16)));
    *(float4*)&a[0][0] = *(const float4*)r0;
    *(float4*)&a[1][0] = *(const float4*)r1;
    *(float4*)&a[2][0] = *(const float4*)r2;
#pragma unroll
    for (int cx = 0; cx < OW; cx += 4) {
        if (OW - cx > 2) {
            *(float4*)&a[0][4] = *(const float4*)(r0 + cx + 4);
            *(float4*)&a[1][4] = *(const float4*)(r1 + cx + 4);
            *(float4*)&a[2][4] = *(const float4*)(r2 + cx + 4);
        }
#pragma unroll
        for (int j = 0; j < 4; ++j) {
            if (cx + j < OW) {
#pragma unroll
                for (int ky = 0; ky < 3; ++ky)
#pragma unroll
                    for (int kx = 0; kx < 3; ++kx) {
                        acc0[cx + j] = fmaf(w0[ky * 3 + kx], a[ky][j + kx], acc0[cx + j]);
                        acc1[cx + j] = fmaf(w1[ky * 3 + kx], a[ky][j + kx], acc1[cx + j]);
                    }
            }
        }
#pragma unroll
        for (int ky = 0; ky < 3; ++ky)
            *(float4*)&a[ky][0] = *(float4*)&a[ky][4];
    }
}

// ================= Kernel A: conv0 (16->16) + conv1 (16->32) ===============
__global__ __launch_bounds__(256, 2)
void k_convA(const float* __restrict__ st,
             const float* __restrict__ cw0, const float* __restrict__ cb0,
             const float* __restrict__ cw1, const float* __restrict__ cb1,
             float* __restrict__ y1)
{
    __shared__ float sY0[16 * 784];
    __shared__ float sIn[2 * 1080];
    __shared__ float sW[2 * 384];
    const int t = threadIdx.x;
    const int bId = blockIdx.x;
    const float* stb = st + (size_t)bId * 14400;

    // ---------------- stage 0: 30x30x16 -> 28x28x16 ----------------
    const int g0 = t >> 5;
    const int row0 = t & 31;
    const bool act0 = row0 < 28;

    float acc[2][28];
#pragma unroll
    for (int o = 0; o < 2; ++o)
#pragma unroll
        for (int c = 0; c < 28; ++c) acc[o][c] = 0.f;

    auto stage_in0 = [&](int ic, int buf) {
        if (t < 225) {
            float4 v = *(const float4*)&stb[ic * 900 + t * 4];
            float vv[4] = {v.x, v.y, v.z, v.w};
            int e = t * 4;
#pragma unroll
            for (int k = 0; k < 4; ++k) {
                int ee = e + k;
                sIn[buf * 1080 + (ee / 30) * 36 + (ee % 30)] = vv[k];
            }
        }
    };
    auto stage_w0 = [&](int ic, int buf) {
        if (t < 192) {
            int oc = t / 12, k = t % 12;
            if (k < 9) sW[buf * 384 + t] = cw0[(oc * 16 + ic) * 9 + k];
        }
    };

    stage_in0(0, 0); stage_w0(0, 0);
#pragma unroll 1
    for (int ic = 0; ic < 16; ++ic) {
        __syncthreads();
        if (ic + 1 < 16) { stage_in0(ic + 1, (ic + 1) & 1); stage_w0(ic + 1, (ic + 1) & 1); }
        if (act0) {
            const int buf = ic & 1;
            float w0r[12] __attribute__((aligned(16)));
            float w1r[12] __attribute__((aligned(16)));
#pragma unroll
            for (int q = 0; q < 3; ++q) {
                *(float4*)&w0r[q * 4] = *(const float4*)&sW[buf * 384 + (2 * g0 + 0) * 12 + q * 4];
                *(float4*)&w1r[q * 4] = *(const float4*)&sW[buf * 384 + (2 * g0 + 1) * 12 + q * 4];
            }
            const float* b = &sIn[buf * 1080 + row0 * 36];
            row_sweep<28>(b, b + 36, b + 72, w0r, w1r, acc[0], acc[1]);
        }
    }
    if (act0) {
#pragma unroll
        for (int o = 0; o < 2; ++o) {
            float bv = cb0[2 * g0 + o];
            float* dst = &sY0[(2 * g0 + o) * 784 + row0 * 28];
#pragma unroll
            for (int cx = 0; cx < 28; cx += 4) {
                float4 v;
                v.x = fmaxf(acc[o][cx + 0] + bv, 0.f);
                v.y = fmaxf(acc[o][cx + 1] + bv, 0.f);
                v.z = fmaxf(acc[o][cx + 2] + bv, 0.f);
                v.w = fmaxf(acc[o][cx + 3] + bv, 0.f);
                *(float4*)&dst[cx] = v;
            }
        }
    }
    __syncthreads();

    // ---------------- stage 1: 28x28x16 -> 26x26x32 ----------------
    auto stage_w1 = [&](int ic, int buf) {
        for (int e = t; e < 384; e += 256) {
            int oc = e / 12, k = e % 12;
            if (k < 9) sW[buf * 384 + e] = cw1[(oc * 16 + ic) * 9 + k];
        }
    };
    stage_w1(0, 0);
    const int g1 = t >> 4;
    const int l1 = t & 15;
#pragma unroll 1
    for (int p = 0; p < 2; ++p) {
        const int row = l1 + 16 * p;
        const bool act1 = row < 26;
        float a1[2][26];
#pragma unroll
        for (int o = 0; o < 2; ++o)
#pragma unroll
            for (int c = 0; c < 26; ++c) a1[o][c] = 0.f;
#pragma unroll 1
        for (int ic = 0; ic < 16; ++ic) {
            __syncthreads();
            int s = p * 16 + ic;
            if (s + 1 < 32) stage_w1((s + 1) & 15, (s + 1) & 1);
            if (act1) {
                const int buf = s & 1;
                float w0r[12] __attribute__((aligned(16)));
                float w1r[12] __attribute__((aligned(16)));
#pragma unroll
                for (int q = 0; q < 3; ++q) {
                    *(float4*)&w0r[q * 4] = *(const float4*)&sW[buf * 384 + (2 * g1 + 0) * 12 + q * 4];
                    *(float4*)&w1r[q * 4] = *(const float4*)&sW[buf * 384 + (2 * g1 + 1) * 12 + q * 4];
                }
                const float* b = &sY0[ic * 784 + row * 28];
                row_sweep<26>(b, b + 28, b + 56, w0r, w1r, a1[0], a1[1]);
            }
        }
        if (act1) {
#pragma unroll
            for (int o = 0; o < 2; ++o) {
                float bv = cb1[2 * g1 + o];
                float* dst = &y1[((size_t)bId * 32 + (2 * g1 + o)) * 676 + row * 26];
#pragma unroll
                for (int cx = 0; cx < 26; cx += 2) {
                    float2 v;
                    v.x = fmaxf(a1[o][cx + 0] + bv, 0.f);
                    v.y = fmaxf(a1[o][cx + 1] + bv, 0.f);
                    *(float2*)&dst[cx] = v;
                }
            }
        }
    }
}

// ================= Kernel B: conv2 (32->16) + conv3 (16->16) ===============
__global__ __launch_bounds__(256, 3)
void k_convB(const float* __restrict__ y1,
             const float* __restrict__ cw2, const float* __restrict__ cb2,
             const float* __restrict__ cw3, const float* __restrict__ cb3,
             float* __restrict__ y3)
{
    __shared__ float sY2[16 * 672];
    __shared__ float sIn[2 * 768];
    __shared__ float sW[2 * 192];
    const int t = threadIdx.x;
    const int bId = blockIdx.x;
    const int g = t >> 5;
    const int row = t & 31;

    // ---------------- stage 2: 26x26x32 -> 24x24x16 ----------------
    const bool act2 = row < 24;
    float acc[2][24];
#pragma unroll
    for (int o = 0; o < 2; ++o)
#pragma unroll
        for (int c = 0; c < 24; ++c) acc[o][c] = 0.f;

    auto stage_in2 = [&](int ic, int buf) {
        if (t < 169) {
            float4 v = *(const float4*)&y1[((size_t)bId * 32 + ic) * 676 + t * 4];
            float vv[4] = {v.x, v.y, v.z, v.w};
            int e = t * 4;
#pragma unroll
            for (int k = 0; k < 4; ++k) {
                int ee = e + k;
                sIn[buf * 768 + (ee / 26) * 28 + (ee % 26)] = vv[k];
            }
        }
    };
    auto stage_w2 = [&](int ic, int buf) {
        if (t < 192) {
            int oc = t / 12, k = t % 12;
            if (k < 9) sW[buf * 192 + t] = cw2[(oc * 32 + ic) * 9 + k];
        }
    };

    stage_in2(0, 0); stage_w2(0, 0);
#pragma unroll 1
    for (int ic = 0; ic < 32; ++ic) {
        __syncthreads();
        if (ic + 1 < 32) { stage_in2(ic + 1, (ic + 1) & 1); stage_w2(ic + 1, (ic + 1) & 1); }
        if (act2) {
            const int buf = ic & 1;
            float w0r[12] __attribute__((aligned(16)));
            float w1r[12] __attribute__((aligned(16)));
#pragma unroll
            for (int q = 0; q < 3; ++q) {
                *(float4*)&w0r[q * 4] = *(const float4*)&sW[buf * 192 + (2 * g + 0) * 12 + q * 4];
                *(float4*)&w1r[q * 4] = *(const float4*)&sW[buf * 192 + (2 * g + 1) * 12 + q * 4];
            }
            const float* b = &sIn[buf * 768 + row * 28];
            row_sweep<24>(b, b + 28, b + 56, w0r, w1r, acc[0], acc[1]);
        }
    }
    if (act2) {
#pragma unroll
        for (int o = 0; o < 2; ++o) {
            float bv = cb2[2 * g + o];
            float* dst = &sY2[(2 * g + o) * 672 + row * 28];
#pragma unroll
            for (int cx = 0; cx < 24; cx += 4) {
                float4 v;
                v.x = fmaxf(acc[o][cx + 0] + bv, 0.f);
                v.y = fmaxf(acc[o][cx + 1] + bv, 0.f);
                v.z = fmaxf(acc[o][cx + 2] + bv, 0.f);
                v.w = fmaxf(acc[o][cx + 3] + bv, 0.f);
                *(float4*)&dst[cx] = v;
            }
        }
    }
    __syncthreads();

    // ---------------- stage 3: 24x24x16 -> 22x22x16 ----------------
    auto stage_w3 = [&](int ic, int buf) {
        if (t < 192) {
            int oc = t / 12, k = t % 12;
            if (k < 9) sW[buf * 192 + t] = cw3[(oc * 16 + ic) * 9 + k];
        }
    };
    stage_w3(0, 0);
    const bool act3 = row < 22;
    float a3[2][22];
#pragma unroll
    for (int o = 0; o < 2; ++o)
#pragma unroll
        for (int c = 0; c < 22; ++c) a3[o][c] = 0.f;
#pragma unroll 1
    for (int ic = 0; ic < 16; ++ic) {
        __syncthreads();
        if (ic + 1 < 16) stage_w3(ic + 1, (ic + 1) & 1);
        if (act3) {
            const int buf = ic & 1;
            float w0r[12] __attribute__((aligned(16)));
            float w1r[12] __attribute__((aligned(16)));
#pragma unroll
            for (int q = 0; q < 3; ++q) {
                *(float4*)&w0r[q * 4] = *(const float4*)&sW[buf * 192 + (2 * g + 0) * 12 + q * 4];
                *(float4*)&w1r[q * 4] = *(const float4*)&sW[buf * 192 + (2 * g + 1) * 12 + q * 4];
            }
            const float* b = &sY2[ic * 672 + row * 28];
            row_sweep<22>(b, b + 28, b + 56, w0r, w1r, a3[0], a3[1]);
        }
    }
    if (act3) {
#pragma unroll
        for (int o = 0; o < 2; ++o) {
            float bv = cb3[2 * g + o];
            float* dst = &y3[(size_t)bId * 7744 + (2 * g + o) * 484 + row * 22];
#pragma unroll
            for (int cx = 0; cx < 22; cx += 2) {
                float2 v;
                v.x = fmaxf(a3[o][cx + 0] + bv, 0.f);
                v.y = fmaxf(a3[o][cx + 1] + bv, 0.f);
                *(float2*)&dst[cx] = v;
            }
        }
    }
}

// ================= Kernel 2: MLP0 GEMM, M=2048 K=7744 N=128, K-split 8 =====
__global__ __launch_bounds__(256)
void k_mlp0(const float* __restrict__ y3, const float* __restrict__ mw0,
            float* __restrict__ part)
{
    __shared__ float As[8 * 32];
    __shared__ float Bs[8 * 128];
    const int t  = threadIdx.x;
    const int mt = blockIdx.x;
    const int ks = blockIdx.y;
    const int m0g = mt * 32;
    const int kb0 = ks * 968;
    const int tm = t >> 4, tn = t & 15;
    const int m0 = tm * 2, n0 = tn * 8;
    float acc[2][8];
#pragma unroll
    for (int r = 0; r < 2; ++r)
#pragma unroll
        for (int c = 0; c < 8; ++c) acc[r][c] = 0.f;

    for (int it = 0; it < 121; ++it) {
        const int kb = kb0 + it * 8;
        if (t < 64) {
            int m = t >> 1, q = t & 1;
            const float4 a4 = *(const float4*)&y3[(m0g + m) * 7744 + kb + q * 4];
            As[(q * 4 + 0) * 32 + m] = a4.x;
            As[(q * 4 + 1) * 32 + m] = a4.y;
            As[(q * 4 + 2) * 32 + m] = a4.z;
            As[(q * 4 + 3) * 32 + m] = a4.w;
        }
        {
            int kk = t >> 5, n4 = t & 31;
            *(float4*)&Bs[kk * 128 + n4 * 4] = *(const float4*)&mw0[(kb + kk) * 128 + n4 * 4];
        }
        __syncthreads();
#pragma unroll
        for (int kk = 0; kk < 8; ++kk) {
            float a0 = As[kk * 32 + m0];
            float a1 = As[kk * 32 + m0 + 1];
            float4 b0 = *(const float4*)&Bs[kk * 128 + n0];
            float4 b1 = *(const float4*)&Bs[kk * 128 + n0 + 4];
            float br[8] = {b0.x, b0.y, b0.z, b0.w, b1.x, b1.y, b1.z, b1.w};
#pragma unroll
            for (int c = 0; c < 8; ++c) {
                acc[0][c] = fmaf(a0, br[c], acc[0][c]);
                acc[1][c] = fmaf(a1, br[c], acc[1][c]);
            }
        }
        __syncthreads();
    }
#pragma unroll
    for (int r = 0; r < 2; ++r)
#pragma unroll
        for (int c = 0; c < 8; ++c)
            part[ks * 262144 + (m0g + m0 + r) * 128 + n0 + c] = acc[r][c];
}

__global__ void k_red(const float* __restrict__ part, const float* __restrict__ mb0,
                      float* __restrict__ z0)
{
    int idx = blockIdx.x * 256 + threadIdx.x;
    int n = idx & 127;
    float s = mb0[n];
#pragma unroll
    for (int k = 0; k < 8; ++k) s += part[k * 262144 + idx];
    z0[idx] = fmaxf(s, 0.f);
}

// ============ Kernel 3: generic [2048x128] @ [128x128] + bias + act ========
__global__ __launch_bounds__(256)
void k_fc(const float* __restrict__ A, const float* __restrict__ W,
          const float* __restrict__ bias, float* __restrict__ C, int do_relu)
{
    __shared__ float As[32 * 129];
    __shared__ float Ws[32 * 128];
    const int t = threadIdx.x;
    const int m0g = blockIdx.x * 32;
#pragma unroll
    for (int r = 0; r < 16; ++r) {
        int e = t + r * 256; int m = e >> 7, k = e & 127;
        As[m * 129 + k] = A[(m0g + m) * 128 + k];
    }
    const int tm = t >> 4, tn = t & 15;
    const int m0 = tm * 2, n0 = tn * 8;
    float acc[2][8];
#pragma unroll
    for (int r = 0; r < 2; ++r)
#pragma unroll
        for (int c = 0; c < 8; ++c) acc[r][c] = 0.f;

    for (int kc = 0; kc < 4; ++kc) {
        __syncthreads();
#pragma unroll
        for (int r = 0; r < 16; ++r) {
            int e = t + r * 256; int kk = e >> 7, n = e & 127;
            Ws[kk * 128 + n] = W[(kc * 32 + kk) * 128 + n];
        }
        __syncthreads();
#pragma unroll
        for (int kk = 0; kk < 32; ++kk) {
            float a0 = As[(m0 + 0) * 129 + kc * 32 + kk];
            float a1 = As[(m0 + 1) * 129 + kc * 32 + kk];
            float4 b0 = *(const float4*)&Ws[kk * 128 + n0];
            float4 b1 = *(const float4*)&Ws[kk * 128 + n0 + 4];
            float br[8] = {b0.x, b0.y, b0.z, b0.w, b1.x, b1.y, b1.z, b1.w};
#pragma unroll
            for (int c = 0; c < 8; ++c) {
                acc[0][c] = fmaf(a0, br[c], acc[0][c]);
                acc[1][c] = fmaf(a1, br[c], acc[1][c]);
            }
        }
    }
#pragma unroll
    for (int c = 0; c < 8; ++c) {
        float bv = bias ? bias[n0 + c] : 0.f;
#pragma unroll
        for (int r = 0; r < 2; ++r) {
            float v = acc[r][c] + bv;
            if (do_relu) v = fmaxf(v, 0.f);
            C[(m0g + m0 + r) * 128 + n0 + c] = v;
        }
    }
}

// ======================= Kernel 4: degree -> dis ===========================
__global__ void k_dis(const float* __restrict__ adj, float* __restrict__ dis)
{
    int bj = blockIdx.x * 256 + threadIdx.x;
    int b = bj >> 6, j = bj & 63;
    float s = 0.f;
#pragma unroll 4
    for (int i = 0; i < 64; ++i) s += adj[b * 4096 + i * 64 + j];
    dis[bj] = s > 0.f ? rsqrtf(fmaxf(s, 1e-30f)) : 0.f;
}

// =========== Kernel 5: emb[b,j,d] = dis_j * sum_i dis_i A[i,j] h[i,d] + gb =
__global__ __launch_bounds__(256)
void k_gcn(const float* __restrict__ adj, const float* __restrict__ dis,
           const float* __restrict__ h, const float* __restrict__ gb,
           float* __restrict__ emb)
{
    __shared__ float adjn[64 * 64];
    __shared__ float hS[64 * 128];
    __shared__ float disS[64];
    const int t = threadIdx.x;
    const int b = blockIdx.x;
    if (t < 64) disS[t] = dis[b * 64 + t];
    __syncthreads();
#pragma unroll
    for (int r = 0; r < 16; ++r) {
        int e = t + r * 256; int i = e >> 6;
        adjn[e] = adj[b * 4096 + e] * disS[i];
    }
#pragma unroll
    for (int r = 0; r < 32; ++r) {
        int e = t + r * 256;
        hS[e] = h[b * 8192 + e];
    }
    __syncthreads();
    const int tj = t >> 5, tn = t & 31;
    const int j0 = tj * 8, n0 = tn * 4;
    float acc[8][4];
#pragma unroll
    for (int jj = 0; jj < 8; ++jj)
#pragma unroll
        for (int c = 0; c < 4; ++c) acc[jj][c] = 0.f;
    for (int i = 0; i < 64; ++i) {
        float4 h4 = *(const float4*)&hS[i * 128 + n0];
        float hr[4] = {h4.x, h4.y, h4.z, h4.w};
#pragma unroll
        for (int jj = 0; jj < 8; ++jj) {
            float a = adjn[i * 64 + j0 + jj];
#pragma unroll
            for (int c = 0; c < 4; ++c) acc[jj][c] = fmaf(a, hr[c], acc[jj][c]);
        }
    }
#pragma unroll
    for (int jj = 0; jj < 8; ++jj) {
        float dj = disS[j0 + jj];
#pragma unroll
        for (int c = 0; c < 4; ++c)
            emb[b * 8192 + (j0 + jj) * 128 + n0 + c] = dj * acc[jj][c] + gb[n0 + c];
    }
}

// ============== Kernel 6: final 128->5 + inactive mask =====================
__global__ __launch_bounds__(256)
void k_head(const float* __restrict__ q1, const float* __restrict__ fw2,
            const float* __restrict__ fb2, const int* __restrict__ maskN,
            float* __restrict__ out)
{
    __shared__ float qs[256 * 33];
    __shared__ float w2s[640];
    __shared__ float b2s[5];
    const int t = threadIdx.x;
    const int m0g = blockIdx.x * 256;
    if (t < 5) b2s[t] = fb2[t];
#pragma unroll
    for (int r = 0; r < 3; ++r) {
        int e = t + r * 256;
        if (e < 640) w2s[e] = fw2[e];
    }
    float acc[5] = {0.f, 0.f, 0.f, 0.f, 0.f};
    for (int kc = 0; kc < 4; ++kc) {
        __syncthreads();
#pragma unroll
        for (int r = 0; r < 32; ++r) {
            int e = t + r * 256; int m = e >> 5, k = e & 31;
            qs[m * 33 + k] = q1[(m0g + m) * 128 + kc * 32 + k];
        }
        __syncthreads();
#pragma unroll
        for (int k = 0; k < 32; ++k) {
            float v = qs[t * 33 + k];
#pragma unroll
            for (int a = 0; a < 5; ++a) acc[a] = fmaf(v, w2s[(kc * 32 + k) * 5 + a], acc[a]);
        }
    }
    const int m = m0g + t;
    const int iz = maskN[m];
#pragma unroll
    for (int a = 0; a < 5; ++a) out[m * 5 + a] = iz ? 0.f : (acc[a] + b2s[a]);
}

// ===========================================================================
extern "C" void kernel_launch(void* const* d_in, const int* in_sizes, int n_in,
                              void* d_out, int out_size, void* d_ws, size_t ws_size,
                              hipStream_t stream)
{
    (void)in_sizes; (void)n_in; (void)out_size;
    const float* states = (const float*)d_in[0];
    const float* adj    = (const float*)d_in[1];
    const void*  inact  = (const void*) d_in[2];
    const float* cw0 = (const float*)d_in[3];  const float* cb0 = (const float*)d_in[4];
    const float* cw1 = (const float*)d_in[5];  const float* cb1 = (const float*)d_in[6];
    const float* cw2 = (const float*)d_in[7];  const float* cb2 = (const float*)d_in[8];
    const float* cw3 = (const float*)d_in[9];  const float* cb3 = (const float*)d_in[10];
    const float* mw0 = (const float*)d_in[11]; const float* mb0 = (const float*)d_in[12];
    const float* mw1 = (const float*)d_in[13]; const float* mb1 = (const float*)d_in[14];
    const float* mw2 = (const float*)d_in[15]; const float* mb2 = (const float*)d_in[16];
    const float* gw  = (const float*)d_in[17]; const float* gb  = (const float*)d_in[18];
    const float* fw0 = (const float*)d_in[19]; const float* fb0 = (const float*)d_in[20];
    const float* fw1 = (const float*)d_in[21]; const float* fb1 = (const float*)d_in[22];
    const float* fw2 = (const float*)d_in[23]; const float* fb2 = (const float*)d_in[24];
    float* out = (float*)d_out;

    // --- workspace layout (round-5 fix): fixed header OUTSIDE dyn region ---
    // [maskN 2048i][dis 2048f][y3 15,859,712f][dyn: max(y1_batch, TAIL)]
    // TAIL = part(2,097,152) + 7 x 262,144 = 3,932,160 fl.
    const size_t HDR_FL = 4096, Y3_FL = 15859712, TAIL_FL = 3932160;
    const size_t Y1_PER_IMG = 21632;
    size_t ws_fl = ws_size / 4;
    int nsplit = 32;
    for (int n = 1; n <= 32; n *= 2) {
        size_t imgs = (2048 + (size_t)n - 1) / n;
        size_t y1fl = imgs * Y1_PER_IMG;
        size_t need = HDR_FL + Y3_FL + (y1fl > TAIL_FL ? y1fl : TAIL_FL);
        if (need <= ws_fl) { nsplit = n; break; }
    }

    float* ws    = (float*)d_ws;
    int*   maskN = (int*)ws;                 // header: mask
    float* dis   = ws + 2048;                // header: dis
    float* y3    = ws + HDR_FL;
    float* dyn   = y3 + Y3_FL;
    float* y1g   = dyn;                      // conv phase only
    float* part  = dyn;                      // post-conv overlay
    float* z0    = part + 2097152;
    float* z1    = z0   + 262144;
    float* feats = z1   + 262144;
    float* h     = feats + 262144;
    float* emb   = h    + 262144;
    float* q0    = emb  + 262144;
    float* q1    = q0   + 262144;            // ends at dyn + 3,932,160

    k_mask<<<1, 256, 0, stream>>>(inact, maskN);

    const int per = (2048 + nsplit - 1) / nsplit;
    for (int s = 0; s < nsplit; ++s) {
        int i0 = s * per;
        int cnt = 2048 - i0; if (cnt > per) cnt = per;
        if (cnt <= 0) break;
        k_convA<<<cnt, 256, 0, stream>>>(states + (size_t)i0 * 14400,
                                         cw0, cb0, cw1, cb1, y1g);
        k_convB<<<cnt, 256, 0, stream>>>(y1g, cw2, cb2, cw3, cb3,
                                         y3 + (size_t)i0 * 7744);
    }

    k_mlp0<<<dim3(64, 8), 256, 0, stream>>>(y3, mw0, part);
    k_red<<<1024, 256, 0, stream>>>(part, mb0, z0);
    k_fc<<<64, 256, 0, stream>>>(z0, mw1, mb1, z1, 1);
    k_fc<<<64, 256, 0, stream>>>(z1, mw2, mb2, feats, 0);
    k_fc<<<64, 256, 0, stream>>>(feats, gw, nullptr, h, 0);
    k_dis<<<8, 256, 0, stream>>>(adj, dis);
    k_gcn<<<32, 256, 0, stream>>>(adj, dis, h, gb, emb);
    k_fc<<<64, 256, 0, stream>>>(emb, fw0, fb0, q0, 1);
    k_fc<<<64, 256, 0, stream>>>(q0, fw1, fb1, q1, 1);
    k_head<<<8, 256, 0, stream>>>(q1, fw2, fb2, maskN, out);
}

// Round 6
// 987.016 us; speedup vs baseline: 3.5498x; 1.0467x over previous
//
#include <hip/hip_runtime.h>

// ---------------------------------------------------------------------------
// MultiDQNGNN. Round 6: barrier-diet conv kernels + wider mlp0 tile.
//  - convA: conv0+conv1 weights fully pre-staged in LDS (oc-stride 196 for
//    conflict-free b128 reads); stage 1 runs with ZERO barriers.
//  - convB: conv3 weights pre-staged (flat copy); stage 3 ZERO barriers.
//  - mlp0: M-tile 64, 4 rows/thread, split-B fragment (2-way banks).
// Workspace: [maskN][dis][y3][dyn(y1 | post-conv tail)] — proven in round 5.
// ---------------------------------------------------------------------------

// ============== Kernel 0: decode `inactives` regardless of layout ==========
__global__ void k_mask(const void* __restrict__ raw, int* __restrict__ mask)
{
    __shared__ unsigned pat[8];
    __shared__ int layout;
    const unsigned char* bts = (const unsigned char*)raw;
    const unsigned* w = (const unsigned*)raw;
    const unsigned short* hw = (const unsigned short*)raw;
    const int t = threadIdx.x;
    if (t < 8) pat[t] = 0;
    __syncthreads();
    unsigned loc[8] = {0,0,0,0,0,0,0,0};
    for (int i = t * 8; i < 2048; i += 256 * 8)
#pragma unroll
        for (int r = 0; r < 8; ++r) loc[r] |= bts[i + r];
#pragma unroll
    for (int r = 0; r < 8; ++r) if (loc[r]) atomicOr(&pat[r], loc[r]);
    __syncthreads();
    if (t == 0) {
        int L = 0;
        bool smallOnly = true;
#pragma unroll
        for (int r = 0; r < 8; ++r) smallOnly = smallOnly && (pat[r] <= 1u);
        if (smallOnly) {
            if (pat[1] | pat[2] | pat[3] | pat[5] | pat[6] | pat[7]) L = 1;  // u8
            else if (pat[4] == 0 && pat[0])                          L = 2;  // i64
            else                                                     L = 0;  // i32
        } else {
            if (pat[1] | pat[5])      L = 4;   // bf16
            else if (pat[2] | pat[6]) L = 3;   // f32
            else if (pat[7])          L = 5;   // f64
        }
        layout = L;
    }
    __syncthreads();
    const int L = layout;
    for (int m = t; m < 2048; m += 256) {
        unsigned v;
        if      (L == 1) v = bts[m];
        else if (L == 2) v = w[2 * m] | w[2 * m + 1];
        else if (L == 3) v = w[m];
        else if (L == 4) v = hw[m];
        else if (L == 5) v = w[2 * m] | w[2 * m + 1];
        else             v = w[m];
        mask[m] = (v != 0u);
    }
}

// ================= sliding-window row sweep (2 ocs, one row) ===============
template<int OW>
__device__ __forceinline__ void row_sweep(
    const float* __restrict__ r0, const float* __restrict__ r1,
    const float* __restrict__ r2,
    const float* __restrict__ w0, const float* __restrict__ w1,
    float* __restrict__ acc0, float* __restrict__ acc1)
{
    float a[3][8] __attribute__((aligned(16)));
    *(float4*)&a[0][0] = *(const float4*)r0;
    *(float4*)&a[1][0] = *(const float4*)r1;
    *(float4*)&a[2][0] = *(const float4*)r2;
#pragma unroll
    for (int cx = 0; cx < OW; cx += 4) {
        if (OW - cx > 2) {
            *(float4*)&a[0][4] = *(const float4*)(r0 + cx + 4);
            *(float4*)&a[1][4] = *(const float4*)(r1 + cx + 4);
            *(float4*)&a[2][4] = *(const float4*)(r2 + cx + 4);
        }
#pragma unroll
        for (int j = 0; j < 4; ++j) {
            if (cx + j < OW) {
#pragma unroll
                for (int ky = 0; ky < 3; ++ky)
#pragma unroll
                    for (int kx = 0; kx < 3; ++kx) {
                        acc0[cx + j] = fmaf(w0[ky * 3 + kx], a[ky][j + kx], acc0[cx + j]);
                        acc1[cx + j] = fmaf(w1[ky * 3 + kx], a[ky][j + kx], acc1[cx + j]);
                    }
            }
        }
#pragma unroll
        for (int ky = 0; ky < 3; ++ky)
            *(float4*)&a[ky][0] = *(float4*)&a[ky][4];
    }
}

// ================= Kernel A: conv0 (16->16) + conv1 (16->32) ===============
// LDS arena (fl): sY0 12544 | regB 6272 (union: stage0 {sIn 2160, sW0 3136}
//                 / stage1 {sW1 6272}) = 18816 fl = 75.3 KB -> 2 blocks/CU.
// Weight layout: [oc]*196 + [ic]*12 + k (196-pad -> b128 reads conflict-free).
__global__ __launch_bounds__(256, 2)
void k_convA(const float* __restrict__ st,
             const float* __restrict__ cw0, const float* __restrict__ cb0,
             const float* __restrict__ cw1, const float* __restrict__ cb1,
             float* __restrict__ y1)
{
    __shared__ float arena[12544 + 6272];
    float* const sY0 = arena;
    float* const regB = arena + 12544;
    float* const sIn = regB;            // stage 0: 2*1080
    float* const sW0 = regB + 2160;     // stage 0: 16*196
    float* const sW1 = regB;            // stage 1: 32*196 (overlays stage-0 bufs)

    const int t = threadIdx.x;
    const int bId = blockIdx.x;
    const float* stb = st + (size_t)bId * 14400;

    // ---- preload ALL conv0 weights: sW0[oc*196 + ic*12 + k] ----
    {
        // t -> (oc = t>>4, ic = t&15); cw0[(oc*16+ic)*9+k] == cw0[t*9+k]
#pragma unroll
        for (int k = 0; k < 9; ++k)
            sW0[(t >> 4) * 196 + (t & 15) * 12 + k] = cw0[t * 9 + k];
    }

    // ---------------- stage 0: 30x30x16 -> 28x28x16 ----------------
    const int g0 = t >> 5;
    const int row0 = t & 31;
    const bool act0 = row0 < 28;

    float acc[2][28];
#pragma unroll
    for (int o = 0; o < 2; ++o)
#pragma unroll
        for (int c = 0; c < 28; ++c) acc[o][c] = 0.f;

    auto stage_in0 = [&](int ic, int buf) {
        if (t < 225) {
            float4 v = *(const float4*)&stb[ic * 900 + t * 4];
            float vv[4] = {v.x, v.y, v.z, v.w};
            int e = t * 4;
#pragma unroll
            for (int k = 0; k < 4; ++k) {
                int ee = e + k;
                sIn[buf * 1080 + (ee / 30) * 36 + (ee % 30)] = vv[k];
            }
        }
    };

    stage_in0(0, 0);
#pragma unroll 1
    for (int ic = 0; ic < 16; ++ic) {
        __syncthreads();
        if (ic + 1 < 16) stage_in0(ic + 1, (ic + 1) & 1);
        if (act0) {
            const int buf = ic & 1;
            float w0r[12] __attribute__((aligned(16)));
            float w1r[12] __attribute__((aligned(16)));
#pragma unroll
            for (int q = 0; q < 3; ++q) {
                *(float4*)&w0r[q * 4] = *(const float4*)&sW0[(2 * g0 + 0) * 196 + ic * 12 + q * 4];
                *(float4*)&w1r[q * 4] = *(const float4*)&sW0[(2 * g0 + 1) * 196 + ic * 12 + q * 4];
            }
            const float* b = &sIn[buf * 1080 + row0 * 36];
            row_sweep<28>(b, b + 36, b + 72, w0r, w1r, acc[0], acc[1]);
        }
    }
    if (act0) {
#pragma unroll
        for (int o = 0; o < 2; ++o) {
            float bv = cb0[2 * g0 + o];
            float* dst = &sY0[(2 * g0 + o) * 784 + row0 * 28];
#pragma unroll
            for (int cx = 0; cx < 28; cx += 4) {
                float4 v;
                v.x = fmaxf(acc[o][cx + 0] + bv, 0.f);
                v.y = fmaxf(acc[o][cx + 1] + bv, 0.f);
                v.z = fmaxf(acc[o][cx + 2] + bv, 0.f);
                v.w = fmaxf(acc[o][cx + 3] + bv, 0.f);
                *(float4*)&dst[cx] = v;
            }
        }
    }
    __syncthreads();   // y0 visible; all stage-0 regB reads complete

    // ---- preload ALL conv1 weights: sW1[oc*196 + ic*12 + k] ----
    for (int e = t; e < 512; e += 256) {      // e -> (oc = e>>4, ic = e&15)
        int oc = e >> 4, ic = e & 15;
#pragma unroll
        for (int k = 0; k < 9; ++k)
            sW1[oc * 196 + ic * 12 + k] = cw1[e * 9 + k];
    }
    __syncthreads();

    // ---------------- stage 1: 28x28x16 -> 26x26x32 (NO barriers) ----------
    const int g1 = t >> 4;
    const int l1 = t & 15;
#pragma unroll 1
    for (int p = 0; p < 2; ++p) {
        const int row = l1 + 16 * p;
        const bool act1 = row < 26;
        float a1[2][26];
#pragma unroll
        for (int o = 0; o < 2; ++o)
#pragma unroll
            for (int c = 0; c < 26; ++c) a1[o][c] = 0.f;
        if (act1) {
#pragma unroll 1
            for (int ic = 0; ic < 16; ++ic) {
                float w0r[12] __attribute__((aligned(16)));
                float w1r[12] __attribute__((aligned(16)));
#pragma unroll
                for (int q = 0; q < 3; ++q) {
                    *(float4*)&w0r[q * 4] = *(const float4*)&sW1[(2 * g1 + 0) * 196 + ic * 12 + q * 4];
                    *(float4*)&w1r[q * 4] = *(const float4*)&sW1[(2 * g1 + 1) * 196 + ic * 12 + q * 4];
                }
                const float* b = &sY0[ic * 784 + row * 28];
                row_sweep<26>(b, b + 28, b + 56, w0r, w1r, a1[0], a1[1]);
            }
#pragma unroll
            for (int o = 0; o < 2; ++o) {
                float bv = cb1[2 * g1 + o];
                float* dst = &y1[((size_t)bId * 32 + (2 * g1 + o)) * 676 + row * 26];
#pragma unroll
                for (int cx = 0; cx < 26; cx += 2) {
                    float2 v;
                    v.x = fmaxf(a1[o][cx + 0] + bv, 0.f);
                    v.y = fmaxf(a1[o][cx + 1] + bv, 0.f);
                    *(float2*)&dst[cx] = v;
                }
            }
        }
    }
}

// ================= Kernel B: conv2 (32->16) + conv3 (16->16) ===============
// LDS (fl): sY2 10752 | regB 2304 (union: stage2 {sIn 1536, sW2 384} /
//           stage3 {sW3 2304 flat}) = 13056 fl = 52.2 KB -> 3 blocks/CU.
__global__ __launch_bounds__(256, 3)
void k_convB(const float* __restrict__ y1,
             const float* __restrict__ cw2, const float* __restrict__ cb2,
             const float* __restrict__ cw3, const float* __restrict__ cb3,
             float* __restrict__ y3)
{
    __shared__ float arena2[10752 + 2304];
    float* const sY2 = arena2;
    float* const regB = arena2 + 10752;
    float* const sIn = regB;            // stage 2: 2*768
    float* const sW2 = regB + 1536;     // stage 2: 2*192
    float* const sW3 = regB;            // stage 3: 2304 flat [oc][ic][9]

    const int t = threadIdx.x;
    const int bId = blockIdx.x;
    const int g = t >> 5;
    const int row = t & 31;

    // ---------------- stage 2: 26x26x32 -> 24x24x16 ----------------
    const bool act2 = row < 24;
    float acc[2][24];
#pragma unroll
    for (int o = 0; o < 2; ++o)
#pragma unroll
        for (int c = 0; c < 24; ++c) acc[o][c] = 0.f;

    auto stage_in2 = [&](int ic, int buf) {
        if (t < 169) {
            float4 v = *(const float4*)&y1[((size_t)bId * 32 + ic) * 676 + t * 4];
            float vv[4] = {v.x, v.y, v.z, v.w};
            int e = t * 4;
#pragma unroll
            for (int k = 0; k < 4; ++k) {
                int ee = e + k;
                sIn[buf * 768 + (ee / 26) * 28 + (ee % 26)] = vv[k];
            }
        }
    };
    auto stage_w2 = [&](int ic, int buf) {
        if (t < 192) {
            int oc = t / 12, k = t % 12;
            if (k < 9) sW2[buf * 192 + t] = cw2[(oc * 32 + ic) * 9 + k];
        }
    };

    stage_in2(0, 0); stage_w2(0, 0);
#pragma unroll 1
    for (int ic = 0; ic < 32; ++ic) {
        __syncthreads();
        if (ic + 1 < 32) { stage_in2(ic + 1, (ic + 1) & 1); stage_w2(ic + 1, (ic + 1) & 1); }
        if (act2) {
            const int buf = ic & 1;
            float w0r[12] __attribute__((aligned(16)));
            float w1r[12] __attribute__((aligned(16)));
#pragma unroll
            for (int q = 0; q < 3; ++q) {
                *(float4*)&w0r[q * 4] = *(const float4*)&sW2[buf * 192 + (2 * g + 0) * 12 + q * 4];
                *(float4*)&w1r[q * 4] = *(const float4*)&sW2[buf * 192 + (2 * g + 1) * 12 + q * 4];
            }
            const float* b = &sIn[buf * 768 + row * 28];
            row_sweep<24>(b, b + 28, b + 56, w0r, w1r, acc[0], acc[1]);
        }
    }
    if (act2) {
#pragma unroll
        for (int o = 0; o < 2; ++o) {
            float bv = cb2[2 * g + o];
            float* dst = &sY2[(2 * g + o) * 672 + row * 28];
#pragma unroll
            for (int cx = 0; cx < 24; cx += 4) {
                float4 v;
                v.x = fmaxf(acc[o][cx + 0] + bv, 0.f);
                v.y = fmaxf(acc[o][cx + 1] + bv, 0.f);
                v.z = fmaxf(acc[o][cx + 2] + bv, 0.f);
                v.w = fmaxf(acc[o][cx + 3] + bv, 0.f);
                *(float4*)&dst[cx] = v;
            }
        }
    }
    __syncthreads();   // y2 visible; stage-2 regB reads complete

    // ---- preload ALL conv3 weights (flat copy, [oc][ic][9]) ----
    for (int e = t; e < 2304; e += 256) sW3[e] = cw3[e];
    __syncthreads();

    // ---------------- stage 3: 24x24x16 -> 22x22x16 (NO barriers) ----------
    const bool act3 = row < 22;
    float a3[2][22];
#pragma unroll
    for (int o = 0; o < 2; ++o)
#pragma unroll
        for (int c = 0; c < 22; ++c) a3[o][c] = 0.f;
    if (act3) {
#pragma unroll 1
        for (int ic = 0; ic < 16; ++ic) {
            float w0r[9], w1r[9];
#pragma unroll
            for (int k = 0; k < 9; ++k) {
                w0r[k] = sW3[((2 * g + 0) * 16 + ic) * 9 + k];
                w1r[k] = sW3[((2 * g + 1) * 16 + ic) * 9 + k];
            }
            const float* b = &sY2[ic * 672 + row * 28];
            row_sweep<22>(b, b + 28, b + 56, w0r, w1r, a3[0], a3[1]);
        }
#pragma unroll
        for (int o = 0; o < 2; ++o) {
            float bv = cb3[2 * g + o];
            float* dst = &y3[(size_t)bId * 7744 + (2 * g + o) * 484 + row * 22];
#pragma unroll
            for (int cx = 0; cx < 22; cx += 2) {
                float2 v;
                v.x = fmaxf(a3[o][cx + 0] + bv, 0.f);
                v.y = fmaxf(a3[o][cx + 1] + bv, 0.f);
                *(float2*)&dst[cx] = v;
            }
        }
    }
}

// ============ Kernel 2: MLP0 GEMM, M=2048 K=7744 N=128, K-split 8 ==========
// M-tile 64, 4 rows/thread; B-fragment split n0 / n0+64 (2-way banks).
__global__ __launch_bounds__(256)
void k_mlp0(const float* __restrict__ y3, const float* __restrict__ mw0,
            float* __restrict__ part)
{
    __shared__ float As[8 * 64];    // [kk][m]
    __shared__ float Bs[8 * 128];   // [kk][n]
    const int t  = threadIdx.x;
    const int mt = blockIdx.x;      // 32 M-tiles
    const int ks = blockIdx.y;      // 8  K-splits
    const int m0g = mt * 64;
    const int kb0 = ks * 968;
    const int tm = t >> 4, tn = t & 15;
    const int m0 = tm * 4, n0 = tn * 4;
    float acc[4][8];
#pragma unroll
    for (int r = 0; r < 4; ++r)
#pragma unroll
        for (int c = 0; c < 8; ++c) acc[r][c] = 0.f;

    for (int it = 0; it < 121; ++it) {
        const int kb = kb0 + it * 8;
        if (t < 128) {
            int m = t >> 1, q = t & 1;
            const float4 a4 = *(const float4*)&y3[(m0g + m) * 7744 + kb + q * 4];
            As[(q * 4 + 0) * 64 + m] = a4.x;
            As[(q * 4 + 1) * 64 + m] = a4.y;
            As[(q * 4 + 2) * 64 + m] = a4.z;
            As[(q * 4 + 3) * 64 + m] = a4.w;
        }
        {
            int kk = t >> 5, n4 = t & 31;
            *(float4*)&Bs[kk * 128 + n4 * 4] = *(const float4*)&mw0[(kb + kk) * 128 + n4 * 4];
        }
        __syncthreads();
#pragma unroll
        for (int kk = 0; kk < 8; ++kk) {
            float ar[4];
#pragma unroll
            for (int r = 0; r < 4; ++r) ar[r] = As[kk * 64 + m0 + r];
            float4 b0 = *(const float4*)&Bs[kk * 128 + n0];
            float4 b1 = *(const float4*)&Bs[kk * 128 + 64 + n0];
            float br[8] = {b0.x, b0.y, b0.z, b0.w, b1.x, b1.y, b1.z, b1.w};
#pragma unroll
            for (int r = 0; r < 4; ++r)
#pragma unroll
                for (int c = 0; c < 8; ++c)
                    acc[r][c] = fmaf(ar[r], br[c], acc[r][c]);
        }
        __syncthreads();
    }
#pragma unroll
    for (int r = 0; r < 4; ++r)
#pragma unroll
        for (int c = 0; c < 8; ++c) {
            int col = (c < 4) ? (n0 + c) : (64 + n0 + c - 4);
            part[ks * 262144 + (m0g + m0 + r) * 128 + col] = acc[r][c];
        }
}

__global__ void k_red(const float* __restrict__ part, const float* __restrict__ mb0,
                      float* __restrict__ z0)
{
    int idx = blockIdx.x * 256 + threadIdx.x;
    int n = idx & 127;
    float s = mb0[n];
#pragma unroll
    for (int k = 0; k < 8; ++k) s += part[k * 262144 + idx];
    z0[idx] = fmaxf(s, 0.f);
}

// ============ Kernel 3: generic [2048x128] @ [128x128] + bias + act ========
__global__ __launch_bounds__(256)
void k_fc(const float* __restrict__ A, const float* __restrict__ W,
          const float* __restrict__ bias, float* __restrict__ C, int do_relu)
{
    __shared__ float As[32 * 129];
    __shared__ float Ws[32 * 128];
    const int t = threadIdx.x;
    const int m0g = blockIdx.x * 32;
#pragma unroll
    for (int r = 0; r < 16; ++r) {
        int e = t + r * 256; int m = e >> 7, k = e & 127;
        As[m * 129 + k] = A[(m0g + m) * 128 + k];
    }
    const int tm = t >> 4, tn = t & 15;
    const int m0 = tm * 2, n0 = tn * 8;
    float acc[2][8];
#pragma unroll
    for (int r = 0; r < 2; ++r)
#pragma unroll
        for (int c = 0; c < 8; ++c) acc[r][c] = 0.f;

    for (int kc = 0; kc < 4; ++kc) {
        __syncthreads();
#pragma unroll
        for (int r = 0; r < 16; ++r) {
            int e = t + r * 256; int kk = e >> 7, n = e & 127;
            Ws[kk * 128 + n] = W[(kc * 32 + kk) * 128 + n];
        }
        __syncthreads();
#pragma unroll
        for (int kk = 0; kk < 32; ++kk) {
            float a0 = As[(m0 + 0) * 129 + kc * 32 + kk];
            float a1 = As[(m0 + 1) * 129 + kc * 32 + kk];
            float4 b0 = *(const float4*)&Ws[kk * 128 + n0];
            float4 b1 = *(const float4*)&Ws[kk * 128 + n0 + 4];
            float br[8] = {b0.x, b0.y, b0.z, b0.w, b1.x, b1.y, b1.z, b1.w};
#pragma unroll
            for (int c = 0; c < 8; ++c) {
                acc[0][c] = fmaf(a0, br[c], acc[0][c]);
                acc[1][c] = fmaf(a1, br[c], acc[1][c]);
            }
        }
    }
#pragma unroll
    for (int c = 0; c < 8; ++c) {
        float bv = bias ? bias[n0 + c] : 0.f;
#pragma unroll
        for (int r = 0; r < 2; ++r) {
            float v = acc[r][c] + bv;
            if (do_relu) v = fmaxf(v, 0.f);
            C[(m0g + m0 + r) * 128 + n0 + c] = v;
        }
    }
}

// ======================= Kernel 4: degree -> dis ===========================
__global__ void k_dis(const float* __restrict__ adj, float* __restrict__ dis)
{
    int bj = blockIdx.x * 256 + threadIdx.x;
    int b = bj >> 6, j = bj & 63;
    float s = 0.f;
#pragma unroll 4
    for (int i = 0; i < 64; ++i) s += adj[b * 4096 + i * 64 + j];
    dis[bj] = s > 0.f ? rsqrtf(fmaxf(s, 1e-30f)) : 0.f;
}

// =========== Kernel 5: emb[b,j,d] = dis_j * sum_i dis_i A[i,j] h[i,d] + gb =
__global__ __launch_bounds__(256)
void k_gcn(const float* __restrict__ adj, const float* __restrict__ dis,
           const float* __restrict__ h, const float* __restrict__ gb,
           float* __restrict__ emb)
{
    __shared__ float adjn[64 * 64];
    __shared__ float hS[64 * 128];
    __shared__ float disS[64];
    const int t = threadIdx.x;
    const int b = blockIdx.x;
    if (t < 64) disS[t] = dis[b * 64 + t];
    __syncthreads();
#pragma unroll
    for (int r = 0; r < 16; ++r) {
        int e = t + r * 256; int i = e >> 6;
        adjn[e] = adj[b * 4096 + e] * disS[i];
    }
#pragma unroll
    for (int r = 0; r < 32; ++r) {
        int e = t + r * 256;
        hS[e] = h[b * 8192 + e];
    }
    __syncthreads();
    const int tj = t >> 5, tn = t & 31;
    const int j0 = tj * 8, n0 = tn * 4;
    float acc[8][4];
#pragma unroll
    for (int jj = 0; jj < 8; ++jj)
#pragma unroll
        for (int c = 0; c < 4; ++c) acc[jj][c] = 0.f;
    for (int i = 0; i < 64; ++i) {
        float4 h4 = *(const float4*)&hS[i * 128 + n0];
        float hr[4] = {h4.x, h4.y, h4.z, h4.w};
#pragma unroll
        for (int jj = 0; jj < 8; ++jj) {
            float a = adjn[i * 64 + j0 + jj];
#pragma unroll
            for (int c = 0; c < 4; ++c) acc[jj][c] = fmaf(a, hr[c], acc[jj][c]);
        }
    }
#pragma unroll
    for (int jj = 0; jj < 8; ++jj) {
        float dj = disS[j0 + jj];
#pragma unroll
        for (int c = 0; c < 4; ++c)
            emb[b * 8192 + (j0 + jj) * 128 + n0 + c] = dj * acc[jj][c] + gb[n0 + c];
    }
}

// ============== Kernel 6: final 128->5 + inactive mask =====================
__global__ __launch_bounds__(256)
void k_head(const float* __restrict__ q1, const float* __restrict__ fw2,
            const float* __restrict__ fb2, const int* __restrict__ maskN,
            float* __restrict__ out)
{
    __shared__ float qs[256 * 33];
    __shared__ float w2s[640];
    __shared__ float b2s[5];
    const int t = threadIdx.x;
    const int m0g = blockIdx.x * 256;
    if (t < 5) b2s[t] = fb2[t];
#pragma unroll
    for (int r = 0; r < 3; ++r) {
        int e = t + r * 256;
        if (e < 640) w2s[e] = fw2[e];
    }
    float acc[5] = {0.f, 0.f, 0.f, 0.f, 0.f};
    for (int kc = 0; kc < 4; ++kc) {
        __syncthreads();
#pragma unroll
        for (int r = 0; r < 32; ++r) {
            int e = t + r * 256; int m = e >> 5, k = e & 31;
            qs[m * 33 + k] = q1[(m0g + m) * 128 + kc * 32 + k];
        }
        __syncthreads();
#pragma unroll
        for (int k = 0; k < 32; ++k) {
            float v = qs[t * 33 + k];
#pragma unroll
            for (int a = 0; a < 5; ++a) acc[a] = fmaf(v, w2s[(kc * 32 + k) * 5 + a], acc[a]);
        }
    }
    const int m = m0g + t;
    const int iz = maskN[m];
#pragma unroll
    for (int a = 0; a < 5; ++a) out[m * 5 + a] = iz ? 0.f : (acc[a] + b2s[a]);
}

// ===========================================================================
extern "C" void kernel_launch(void* const* d_in, const int* in_sizes, int n_in,
                              void* d_out, int out_size, void* d_ws, size_t ws_size,
                              hipStream_t stream)
{
    (void)in_sizes; (void)n_in; (void)out_size;
    const float* states = (const float*)d_in[0];
    const float* adj    = (const float*)d_in[1];
    const void*  inact  = (const void*) d_in[2];
    const float* cw0 = (const float*)d_in[3];  const float* cb0 = (const float*)d_in[4];
    const float* cw1 = (const float*)d_in[5];  const float* cb1 = (const float*)d_in[6];
    const float* cw2 = (const float*)d_in[7];  const float* cb2 = (const float*)d_in[8];
    const float* cw3 = (const float*)d_in[9];  const float* cb3 = (const float*)d_in[10];
    const float* mw0 = (const float*)d_in[11]; const float* mb0 = (const float*)d_in[12];
    const float* mw1 = (const float*)d_in[13]; const float* mb1 = (const float*)d_in[14];
    const float* mw2 = (const float*)d_in[15]; const float* mb2 = (const float*)d_in[16];
    const float* gw  = (const float*)d_in[17]; const float* gb  = (const float*)d_in[18];
    const float* fw0 = (const float*)d_in[19]; const float* fb0 = (const float*)d_in[20];
    const float* fw1 = (const float*)d_in[21]; const float* fb1 = (const float*)d_in[22];
    const float* fw2 = (const float*)d_in[23]; const float* fb2 = (const float*)d_in[24];
    float* out = (float*)d_out;

    // [maskN 2048i][dis 2048f][y3 15,859,712f][dyn: max(y1_batch, TAIL)]
    const size_t HDR_FL = 4096, Y3_FL = 15859712, TAIL_FL = 3932160;
    const size_t Y1_PER_IMG = 21632;
    size_t ws_fl = ws_size / 4;
    int nsplit = 32;
    for (int n = 1; n <= 32; n *= 2) {
        size_t imgs = (2048 + (size_t)n - 1) / n;
        size_t y1fl = imgs * Y1_PER_IMG;
        size_t need = HDR_FL + Y3_FL + (y1fl > TAIL_FL ? y1fl : TAIL_FL);
        if (need <= ws_fl) { nsplit = n; break; }
    }

    float* ws    = (float*)d_ws;
    int*   maskN = (int*)ws;
    float* dis   = ws + 2048;
    float* y3    = ws + HDR_FL;
    float* dyn   = y3 + Y3_FL;
    float* y1g   = dyn;
    float* part  = dyn;
    float* z0    = part + 2097152;
    float* z1    = z0   + 262144;
    float* feats = z1   + 262144;
    float* h     = feats + 262144;
    float* emb   = h    + 262144;
    float* q0    = emb  + 262144;
    float* q1    = q0   + 262144;

    k_mask<<<1, 256, 0, stream>>>(inact, maskN);

    const int per = (2048 + nsplit - 1) / nsplit;
    for (int s = 0; s < nsplit; ++s) {
        int i0 = s * per;
        int cnt = 2048 - i0; if (cnt > per) cnt = per;
        if (cnt <= 0) break;
        k_convA<<<cnt, 256, 0, stream>>>(states + (size_t)i0 * 14400,
                                         cw0, cb0, cw1, cb1, y1g);
        k_convB<<<cnt, 256, 0, stream>>>(y1g, cw2, cb2, cw3, cb3,
                                         y3 + (size_t)i0 * 7744);
    }

    k_mlp0<<<dim3(32, 8), 256, 0, stream>>>(y3, mw0, part);
    k_red<<<1024, 256, 0, stream>>>(part, mb0, z0);
    k_fc<<<64, 256, 0, stream>>>(z0, mw1, mb1, z1, 1);
    k_fc<<<64, 256, 0, stream>>>(z1, mw2, mb2, feats, 0);
    k_fc<<<64, 256, 0, stream>>>(feats, gw, nullptr, h, 0);
    k_dis<<<8, 256, 0, stream>>>(adj, dis);
    k_gcn<<<32, 256, 0, stream>>>(adj, dis, h, gb, emb);
    k_fc<<<64, 256, 0, stream>>>(emb, fw0, fb0, q0, 1);
    k_fc<<<64, 256, 0, stream>>>(q0, fw1, fb1, q1, 1);
    k_head<<<8, 256, 0, stream>>>(q1, fw2, fb2, maskN, out);
}